// Round 1
// baseline (69.097 us; speedup 1.0000x reference)
//
#include <hip/hip_runtime.h>
#include <math.h>

#define ALPHA 0.99f

constexpr int R   = 16;            // samples per thread
constexpr int BT  = 256;           // threads per block
constexpr int TILE = R * BT;       // 4096 samples per block
constexpr int NROWS = 16;
constexpr int NS  = 1 << 21;       // 2097152 samples per row
constexpr int BPR = NS / TILE;     // 512 blocks per row
constexpr int NBLOCKS = NROWS * BPR; // 8192

// exact double-precision powers of alpha at compile time
constexpr double dpow(double a, long n) {
    double r = 1.0;
    while (n > 0) { if (n & 1) r *= a; a *= a; n >>= 1; }
    return r;
}
constexpr double s2c_calc() {       // sum_{t=1..R} alpha^{2t}
    double s = 0.0, p = 1.0;
    for (int t = 1; t <= R; ++t) { p *= 0.99 * 0.99; s += p; }
    return s;
}
constexpr double csum_calc() {      // sum_{i=0..BT-1} alpha^{2*R*i}
    double s = 0.0;
    for (int i = 0; i < BT; ++i) s += dpow(0.99, 32L * i);
    return s;
}

constexpr float W1    = (float)dpow(0.99, 16);    // scan weights: alpha^(16*s)
constexpr float W2    = (float)dpow(0.99, 32);
constexpr float W4    = (float)dpow(0.99, 64);
constexpr float W8    = (float)dpow(0.99, 128);
constexpr float W16   = (float)dpow(0.99, 256);
constexpr float W32   = (float)dpow(0.99, 512);
constexpr float A1024 = (float)dpow(0.99, 1024);  // wave span decay
constexpr float A2048 = (float)dpow(0.99, 2048);
constexpr float A3072 = (float)dpow(0.99, 3072);
constexpr float S2C   = (float)s2c_calc();
constexpr float CCONST = (float)(s2c_calc() * csum_calc());
constexpr float L2A16 = -0.231993109f;            // 16*log2(0.99)

// K1: per-block (A, B, Z): BlockSumSq(Y_in) = A + B*Y_in + CCONST*Y_in^2,
//     Z = zero-state filter output at end of block tile.
__global__ __launch_bounds__(256) void k_scan(const float* __restrict__ x,
                                              float* __restrict__ blk) {
    const int b   = blockIdx.x;
    const int row = b / BPR;
    const int jb  = b % BPR;
    const int tid = threadIdx.x;
    const int lane = tid & 63, wid = tid >> 6;

    const size_t base = (size_t)row * NS + (size_t)jb * TILE + (size_t)tid * R;
    const float4* xp = reinterpret_cast<const float4*>(x + base);
    float4 v0 = xp[0], v1 = xp[1], v2 = xp[2], v3 = xp[3];

    const bool rowstart = (jb == 0) && (tid == 0);
    float xm1 = rowstart ? 0.0f : x[base - 1];

    float xs[16] = { v0.x, v0.y, v0.z, v0.w,
                     v1.x, v1.y, v1.z, v1.w,
                     v2.x, v2.y, v2.z, v2.w,
                     v3.x, v3.y, v3.z, v3.w };

    // serial zero-state pass over 16 samples
    float mprev = ALPHA * xm1;
    float z = 0.0f, p = 1.0f, S0 = 0.0f, S1 = 0.0f;
#pragma unroll
    for (int t = 0; t < 16; ++t) {
        float m  = ALPHA * xs[t];
        float bb = m - mprev;
        if (rowstart && t == 0) bb = xs[0];   // y[0] = x[0] exactly
        z = fmaf(ALPHA, z, bb);               // z_t = a*z_{t-1} + b_t
        p *= ALPHA;                           // p = alpha^t
        S0 = fmaf(z, z, S0);
        S1 = fmaf(z, p, S1);
        mprev = m;
    }

    // weighted inclusive scan of per-thread carries z (weight alpha^16 per hop)
    float incl = z;
    { float t1 = __shfl_up(incl, 1);  if (lane >= 1)  incl = fmaf(W1,  t1, incl); }
    { float t1 = __shfl_up(incl, 2);  if (lane >= 2)  incl = fmaf(W2,  t1, incl); }
    { float t1 = __shfl_up(incl, 4);  if (lane >= 4)  incl = fmaf(W4,  t1, incl); }
    { float t1 = __shfl_up(incl, 8);  if (lane >= 8)  incl = fmaf(W8,  t1, incl); }
    { float t1 = __shfl_up(incl, 16); if (lane >= 16) incl = fmaf(W16, t1, incl); }
    { float t1 = __shfl_up(incl, 32); if (lane >= 32) incl = fmaf(W32, t1, incl); }

    __shared__ float waveZ[4];
    __shared__ float pa[4], pb[4];
    __shared__ float sZb;
    if (lane == 63) waveZ[wid] = incl;
    __syncthreads();

    // state entering this wave (block zero-state)
    float P = 0.0f;
    for (int u = 0; u < wid; ++u) P = fmaf(A1024, P, waveZ[u]);

    // exclusive carry entering this thread
    float excl = __shfl_up(incl, 1);
    if (lane == 0) excl = 0.0f;
    float wl = exp2f((float)lane * L2A16);     // alpha^(16*lane)
    float E  = fmaf(wl, P, excl);

    // thread contribution, expanded in block-incoming state Y:
    // S0 + 2*S1*y_in + S2C*y_in^2, y_in = E + Q*Y
    float ai = fmaf(S2C * E, E, fmaf(2.0f * S1, E, S0));
    float qw = (wid == 0) ? 1.0f : (wid == 1) ? A1024 : (wid == 2) ? A2048 : A3072;
    float Qi = wl * qw;                        // alpha^(16*tid)
    float bi = 2.0f * Qi * fmaf(S2C, E, S1);

    // block zero-state output
    if (tid == 255) sZb = fmaf(A1024, P, incl);

    // reduce ai, bi across wave then block
    for (int d = 32; d; d >>= 1) { ai += __shfl_xor(ai, d); bi += __shfl_xor(bi, d); }
    if (lane == 0) { pa[wid] = ai; pb[wid] = bi; }
    __syncthreads();

    if (tid == 0) {
        float A = pa[0] + pa[1] + pa[2] + pa[3];
        float B = pb[0] + pb[1] + pb[2] + pb[3];
        blk[(size_t)b * 3 + 0] = A;
        blk[(size_t)b * 3 + 1] = B;
        blk[(size_t)b * 3 + 2] = sZb;
    }
}

// K2: per-row total sum of squares -> gain. Y_in(block j) = Z_{j-1}
// (alpha^4096 ~ 1.3e-18, chain term negligible => fully parallel).
__global__ __launch_bounds__(256) void k_gain(const float* __restrict__ blk,
                                              float* __restrict__ gains) {
    const int row = blockIdx.x;
    const int tid = threadIdx.x;
    const int lane = tid & 63, wid = tid >> 6;

    float s = 0.0f;
    for (int j = tid; j < BPR; j += BT) {
        size_t idx = (size_t)row * BPR + j;
        float A  = blk[idx * 3 + 0];
        float B  = blk[idx * 3 + 1];
        float Zp = (j == 0) ? 0.0f : blk[idx * 3 - 1];  // (idx-1)*3+2
        s += fmaf(CCONST, Zp * Zp, fmaf(B, Zp, A));
    }
    for (int d = 32; d; d >>= 1) s += __shfl_xor(s, d);
    __shared__ float ps[4];
    if (lane == 0) ps[wid] = s;
    __syncthreads();
    if (tid == 0) {
        float total = ps[0] + ps[1] + ps[2] + ps[3];
        float ms   = total * (1.0f / (float)NS);
        float lufs = -0.691f + 10.0f * log10f(ms + 1e-8f);
        float gdb  = fminf(fmaxf(-23.0f - lufs, -30.0f), 30.0f);
        gains[row] = exp2f(gdb * 0.1660964047f);        // 10^(gdb/20)
    }
}

// K3: out = x * gain[row], float4 vectorized
__global__ __launch_bounds__(256) void k_scale(const float* __restrict__ x,
                                               const float* __restrict__ gains,
                                               float* __restrict__ out, int n4) {
    int i = blockIdx.x * blockDim.x + threadIdx.x;
    const int stride = gridDim.x * blockDim.x;
    const float4* xi = reinterpret_cast<const float4*>(x);
    float4* oo = reinterpret_cast<float4*>(out);
    for (; i < n4; i += stride) {
        int row = i >> 19;                  // NS/4 = 2^19 float4 per row
        float g = gains[row];
        float4 v = xi[i];
        v.x *= g; v.y *= g; v.z *= g; v.w *= g;
        oo[i] = v;
    }
}

extern "C" void kernel_launch(void* const* d_in, const int* in_sizes, int n_in,
                              void* d_out, int out_size, void* d_ws, size_t ws_size,
                              hipStream_t stream) {
    const float* x = (const float*)d_in[0];
    float* out = (float*)d_out;
    float* blk = (float*)d_ws;                 // NBLOCKS*3 floats
    float* gains = blk + (size_t)NBLOCKS * 3;  // 16 floats

    k_scan<<<NBLOCKS, BT, 0, stream>>>(x, blk);
    k_gain<<<NROWS, BT, 0, stream>>>(blk, gains);
    int n4 = (NROWS * NS) / 4;
    k_scale<<<2048, BT, 0, stream>>>(x, gains, out, n4);
}

// Round 3
// 68.890 us; speedup vs baseline: 1.0030x; 1.0030x over previous
//
#include <hip/hip_runtime.h>
#include <math.h>

#define ALPHA 0.99f

typedef float f4 __attribute__((ext_vector_type(4)));  // native vector, OK for nontemporal builtins

constexpr int R   = 16;            // samples per thread
constexpr int BT  = 256;           // threads per block
constexpr int TILE = R * BT;       // 4096 samples per block
constexpr int NROWS = 16;
constexpr int NS  = 1 << 21;       // 2097152 samples per row
constexpr int BPR = NS / TILE;     // 512 blocks per row
constexpr int NBLOCKS = NROWS * BPR; // 8192

// exact double-precision powers of alpha at compile time
constexpr double dpow(double a, long n) {
    double r = 1.0;
    while (n > 0) { if (n & 1) r *= a; a *= a; n >>= 1; }
    return r;
}
constexpr double s2c_calc() {       // sum_{t=1..R} alpha^{2t}
    double s = 0.0, p = 1.0;
    for (int t = 1; t <= R; ++t) { p *= 0.99 * 0.99; s += p; }
    return s;
}
constexpr double csum_calc() {      // sum_{i=0..BT-1} alpha^{2*R*i}
    double s = 0.0;
    for (int i = 0; i < BT; ++i) s += dpow(0.99, 32L * i);
    return s;
}

constexpr float W1    = (float)dpow(0.99, 16);    // scan weights: alpha^(16*s)
constexpr float W2    = (float)dpow(0.99, 32);
constexpr float W4    = (float)dpow(0.99, 64);
constexpr float W8    = (float)dpow(0.99, 128);
constexpr float W16   = (float)dpow(0.99, 256);
constexpr float W32   = (float)dpow(0.99, 512);
constexpr float A1024 = (float)dpow(0.99, 1024);  // wave span decay
constexpr float A2048 = (float)dpow(0.99, 2048);
constexpr float A3072 = (float)dpow(0.99, 3072);
constexpr float S2C   = (float)s2c_calc();
constexpr float CCONST = (float)(s2c_calc() * csum_calc());
constexpr float L2A16 = -0.231993109f;            // 16*log2(0.99)

// K1: per-block (A, B, Z): BlockSumSq(Y_in) = A + B*Y_in + CCONST*Y_in^2,
//     Z = zero-state filter output at end of block tile.
//     x loads are NORMAL (we want x resident in L3 for the scale pass).
__global__ __launch_bounds__(256) void k_scan(const float* __restrict__ x,
                                              float* __restrict__ blk) {
    const int b   = blockIdx.x;
    const int row = b / BPR;
    const int jb  = b % BPR;
    const int tid = threadIdx.x;
    const int lane = tid & 63, wid = tid >> 6;

    const size_t base = (size_t)row * NS + (size_t)jb * TILE + (size_t)tid * R;
    const float4* xp = reinterpret_cast<const float4*>(x + base);
    float4 v0 = xp[0], v1 = xp[1], v2 = xp[2], v3 = xp[3];

    const bool rowstart = (jb == 0) && (tid == 0);
    float xm1 = rowstart ? 0.0f : x[base - 1];

    float xs[16] = { v0.x, v0.y, v0.z, v0.w,
                     v1.x, v1.y, v1.z, v1.w,
                     v2.x, v2.y, v2.z, v2.w,
                     v3.x, v3.y, v3.z, v3.w };

    // serial zero-state pass over 16 samples
    float mprev = ALPHA * xm1;
    float z = 0.0f, p = 1.0f, S0 = 0.0f, S1 = 0.0f;
#pragma unroll
    for (int t = 0; t < 16; ++t) {
        float m  = ALPHA * xs[t];
        float bb = m - mprev;
        if (rowstart && t == 0) bb = xs[0];   // y[0] = x[0] exactly
        z = fmaf(ALPHA, z, bb);               // z_t = a*z_{t-1} + b_t
        p *= ALPHA;                           // p = alpha^t
        S0 = fmaf(z, z, S0);
        S1 = fmaf(z, p, S1);
        mprev = m;
    }

    // weighted inclusive scan of per-thread carries z (weight alpha^16 per hop)
    float incl = z;
    { float t1 = __shfl_up(incl, 1);  if (lane >= 1)  incl = fmaf(W1,  t1, incl); }
    { float t1 = __shfl_up(incl, 2);  if (lane >= 2)  incl = fmaf(W2,  t1, incl); }
    { float t1 = __shfl_up(incl, 4);  if (lane >= 4)  incl = fmaf(W4,  t1, incl); }
    { float t1 = __shfl_up(incl, 8);  if (lane >= 8)  incl = fmaf(W8,  t1, incl); }
    { float t1 = __shfl_up(incl, 16); if (lane >= 16) incl = fmaf(W16, t1, incl); }
    { float t1 = __shfl_up(incl, 32); if (lane >= 32) incl = fmaf(W32, t1, incl); }

    __shared__ float waveZ[4];
    __shared__ float pa[4], pb[4];
    __shared__ float sZb;
    if (lane == 63) waveZ[wid] = incl;
    __syncthreads();

    // state entering this wave (block zero-state)
    float P = 0.0f;
    for (int u = 0; u < wid; ++u) P = fmaf(A1024, P, waveZ[u]);

    // exclusive carry entering this thread
    float excl = __shfl_up(incl, 1);
    if (lane == 0) excl = 0.0f;
    float wl = exp2f((float)lane * L2A16);     // alpha^(16*lane)
    float E  = fmaf(wl, P, excl);

    // thread contribution, expanded in block-incoming state Y:
    // S0 + 2*S1*y_in + S2C*y_in^2, y_in = E + Q*Y
    float ai = fmaf(S2C * E, E, fmaf(2.0f * S1, E, S0));
    float qw = (wid == 0) ? 1.0f : (wid == 1) ? A1024 : (wid == 2) ? A2048 : A3072;
    float Qi = wl * qw;                        // alpha^(16*tid)
    float bi = 2.0f * Qi * fmaf(S2C, E, S1);

    // block zero-state output
    if (tid == 255) sZb = fmaf(A1024, P, incl);

    // reduce ai, bi across wave then block
    for (int d = 32; d; d >>= 1) { ai += __shfl_xor(ai, d); bi += __shfl_xor(bi, d); }
    if (lane == 0) { pa[wid] = ai; pb[wid] = bi; }
    __syncthreads();

    if (tid == 0) {
        float A = pa[0] + pa[1] + pa[2] + pa[3];
        float B = pb[0] + pb[1] + pb[2] + pb[3];
        blk[(size_t)b * 3 + 0] = A;
        blk[(size_t)b * 3 + 1] = B;
        blk[(size_t)b * 3 + 2] = sZb;
    }
}

// K2 (fused gain+scale): each block covers exactly one 4096-float4 segment of
// one row (128 blocks per row). It first redundantly reduces its row's 512
// block-stats (L2-resident, ~6 KB) to the row gain, then scales its segment.
// x is read with NT loads (single use; keep L3 clean), out written with NT
// stores (no reuse; don't evict x for the other blocks still reading it).
__global__ __launch_bounds__(256) void k_scale(const float* __restrict__ x,
                                               const float* __restrict__ blk,
                                               float* __restrict__ out) {
    const int row = blockIdx.x >> 7;     // 128 blocks per row
    const int seg = blockIdx.x & 127;
    const int tid = threadIdx.x;
    const int lane = tid & 63, wid = tid >> 6;

    // ---- row gain (redundant per block, deterministic) ----
    float s = 0.0f;
#pragma unroll
    for (int k = 0; k < 2; ++k) {
        int j = tid + k * BT;                       // 0..511
        size_t idx = (size_t)row * BPR + j;
        float A  = blk[idx * 3 + 0];
        float B  = blk[idx * 3 + 1];
        float Zp = (j == 0) ? 0.0f : blk[idx * 3 - 1];  // (idx-1)*3+2
        s += fmaf(CCONST, Zp * Zp, fmaf(B, Zp, A));
    }
    for (int d = 32; d; d >>= 1) s += __shfl_xor(s, d);
    __shared__ float ps[4];
    __shared__ float sgain;
    if (lane == 0) ps[wid] = s;
    __syncthreads();
    if (tid == 0) {
        float total = ps[0] + ps[1] + ps[2] + ps[3];
        float ms   = total * (1.0f / (float)NS);
        float lufs = -0.691f + 10.0f * log10f(ms + 1e-8f);
        float gdb  = fminf(fmaxf(-23.0f - lufs, -30.0f), 30.0f);
        sgain = exp2f(gdb * 0.1660964047f);         // 10^(gdb/20)
    }
    __syncthreads();
    const float g = sgain;

    // ---- scale this block's segment ----
    const size_t base4 = (size_t)row * (NS / 4) + (size_t)seg * 4096;
    const f4* xi = reinterpret_cast<const f4*>(x) + base4;
    f4* oo = reinterpret_cast<f4*>(out) + base4;
#pragma unroll 4
    for (int k = 0; k < 16; ++k) {
        int i = k * BT + tid;
        f4 v = __builtin_nontemporal_load(xi + i);
        v *= g;
        __builtin_nontemporal_store(v, oo + i);
    }
}

extern "C" void kernel_launch(void* const* d_in, const int* in_sizes, int n_in,
                              void* d_out, int out_size, void* d_ws, size_t ws_size,
                              hipStream_t stream) {
    const float* x = (const float*)d_in[0];
    float* out = (float*)d_out;
    float* blk = (float*)d_ws;                 // NBLOCKS*3 floats

    k_scan<<<NBLOCKS, BT, 0, stream>>>(x, blk);
    k_scale<<<2048, BT, 0, stream>>>(x, blk, out);
}

// Round 4
// 65.734 us; speedup vs baseline: 1.0512x; 1.0480x over previous
//
#include <hip/hip_runtime.h>
#include <math.h>

#define ALPHA 0.99f

typedef float f4 __attribute__((ext_vector_type(4)));  // native vector, OK for nontemporal builtins

constexpr int R   = 16;            // samples per thread
constexpr int BT  = 256;           // threads per block
constexpr int TILE = R * BT;       // 4096 samples per block
constexpr int NROWS = 16;
constexpr int NS  = 1 << 21;       // 2097152 samples per row
constexpr int BPR = NS / TILE;     // 512 blocks per row
constexpr int NBLOCKS = NROWS * BPR; // 8192

// exact double-precision powers of alpha at compile time
constexpr double dpow(double a, long n) {
    double r = 1.0;
    while (n > 0) { if (n & 1) r *= a; a *= a; n >>= 1; }
    return r;
}
constexpr double s2c_calc() {       // sum_{t=1..R} alpha^{2t}
    double s = 0.0, p = 1.0;
    for (int t = 1; t <= R; ++t) { p *= 0.99 * 0.99; s += p; }
    return s;
}
constexpr double csum_calc() {      // sum_{i=0..BT-1} alpha^{2*R*i}
    double s = 0.0;
    for (int i = 0; i < BT; ++i) s += dpow(0.99, 32L * i);
    return s;
}

constexpr float W1    = (float)dpow(0.99, 16);    // scan weights: alpha^(16*s)
constexpr float W2    = (float)dpow(0.99, 32);
constexpr float W4    = (float)dpow(0.99, 64);
constexpr float W8    = (float)dpow(0.99, 128);
constexpr float W16   = (float)dpow(0.99, 256);
constexpr float W32   = (float)dpow(0.99, 512);
constexpr float A1024 = (float)dpow(0.99, 1024);  // wave span decay
constexpr float A2048 = (float)dpow(0.99, 2048);
constexpr float A3072 = (float)dpow(0.99, 3072);
constexpr float S2C   = (float)s2c_calc();
constexpr float CCONST = (float)(s2c_calc() * csum_calc());
constexpr float L2A16 = -0.231993109f;            // 16*log2(0.99)

// K1: per-block (A, B, Z): BlockSumSq(Y_in) = A + B*Y_in + CCONST*Y_in^2,
//     Z = zero-state filter output at end of block tile.
//     x loads are NORMAL (we want x resident in L3 for the scale pass).
__global__ __launch_bounds__(256) void k_scan(const float* __restrict__ x,
                                              float* __restrict__ blk) {
    const int b   = blockIdx.x;
    const int row = b / BPR;
    const int jb  = b % BPR;
    const int tid = threadIdx.x;
    const int lane = tid & 63, wid = tid >> 6;

    const size_t base = (size_t)row * NS + (size_t)jb * TILE + (size_t)tid * R;
    const float4* xp = reinterpret_cast<const float4*>(x + base);
    float4 v0 = xp[0], v1 = xp[1], v2 = xp[2], v3 = xp[3];

    const bool rowstart = (jb == 0) && (tid == 0);
    float xm1 = rowstart ? 0.0f : x[base - 1];

    float xs[16] = { v0.x, v0.y, v0.z, v0.w,
                     v1.x, v1.y, v1.z, v1.w,
                     v2.x, v2.y, v2.z, v2.w,
                     v3.x, v3.y, v3.z, v3.w };

    // serial zero-state pass over 16 samples
    float mprev = ALPHA * xm1;
    float z = 0.0f, p = 1.0f, S0 = 0.0f, S1 = 0.0f;
#pragma unroll
    for (int t = 0; t < 16; ++t) {
        float m  = ALPHA * xs[t];
        float bb = m - mprev;
        if (rowstart && t == 0) bb = xs[0];   // y[0] = x[0] exactly
        z = fmaf(ALPHA, z, bb);               // z_t = a*z_{t-1} + b_t
        p *= ALPHA;                           // p = alpha^t
        S0 = fmaf(z, z, S0);
        S1 = fmaf(z, p, S1);
        mprev = m;
    }

    // weighted inclusive scan of per-thread carries z (weight alpha^16 per hop)
    float incl = z;
    { float t1 = __shfl_up(incl, 1);  if (lane >= 1)  incl = fmaf(W1,  t1, incl); }
    { float t1 = __shfl_up(incl, 2);  if (lane >= 2)  incl = fmaf(W2,  t1, incl); }
    { float t1 = __shfl_up(incl, 4);  if (lane >= 4)  incl = fmaf(W4,  t1, incl); }
    { float t1 = __shfl_up(incl, 8);  if (lane >= 8)  incl = fmaf(W8,  t1, incl); }
    { float t1 = __shfl_up(incl, 16); if (lane >= 16) incl = fmaf(W16, t1, incl); }
    { float t1 = __shfl_up(incl, 32); if (lane >= 32) incl = fmaf(W32, t1, incl); }

    __shared__ float waveZ[4];
    __shared__ float pa[4], pb[4];
    __shared__ float sZb;
    if (lane == 63) waveZ[wid] = incl;
    __syncthreads();

    // state entering this wave (block zero-state)
    float P = 0.0f;
    for (int u = 0; u < wid; ++u) P = fmaf(A1024, P, waveZ[u]);

    // exclusive carry entering this thread
    float excl = __shfl_up(incl, 1);
    if (lane == 0) excl = 0.0f;
    float wl = exp2f((float)lane * L2A16);     // alpha^(16*lane)
    float E  = fmaf(wl, P, excl);

    // thread contribution, expanded in block-incoming state Y:
    // S0 + 2*S1*y_in + S2C*y_in^2, y_in = E + Q*Y
    float ai = fmaf(S2C * E, E, fmaf(2.0f * S1, E, S0));
    float qw = (wid == 0) ? 1.0f : (wid == 1) ? A1024 : (wid == 2) ? A2048 : A3072;
    float Qi = wl * qw;                        // alpha^(16*tid)
    float bi = 2.0f * Qi * fmaf(S2C, E, S1);

    // block zero-state output
    if (tid == 255) sZb = fmaf(A1024, P, incl);

    // reduce ai, bi across wave then block
    for (int d = 32; d; d >>= 1) { ai += __shfl_xor(ai, d); bi += __shfl_xor(bi, d); }
    if (lane == 0) { pa[wid] = ai; pb[wid] = bi; }
    __syncthreads();

    if (tid == 0) {
        float A = pa[0] + pa[1] + pa[2] + pa[3];
        float B = pb[0] + pb[1] + pb[2] + pb[3];
        blk[(size_t)b * 3 + 0] = A;
        blk[(size_t)b * 3 + 1] = B;
        blk[(size_t)b * 3 + 2] = sZb;
    }
}

// K2 (fused gain+scale): each block covers exactly one 4096-float4 segment of
// one row (128 blocks per row). It first redundantly reduces its row's 512
// block-stats (L2-resident, ~6 KB) to the row gain, then scales its segment.
// x is read with NORMAL loads (should hit L3 — allocated there by k_scan);
// out written with NT stores (no reuse; don't evict x from L3 while the
// other blocks are still reading it).
__global__ __launch_bounds__(256) void k_scale(const float* __restrict__ x,
                                               const float* __restrict__ blk,
                                               float* __restrict__ out) {
    const int row = blockIdx.x >> 7;     // 128 blocks per row
    const int seg = blockIdx.x & 127;
    const int tid = threadIdx.x;
    const int lane = tid & 63, wid = tid >> 6;

    // ---- row gain (redundant per block, deterministic) ----
    float s = 0.0f;
#pragma unroll
    for (int k = 0; k < 2; ++k) {
        int j = tid + k * BT;                       // 0..511
        size_t idx = (size_t)row * BPR + j;
        float A  = blk[idx * 3 + 0];
        float B  = blk[idx * 3 + 1];
        float Zp = (j == 0) ? 0.0f : blk[idx * 3 - 1];  // (idx-1)*3+2
        s += fmaf(CCONST, Zp * Zp, fmaf(B, Zp, A));
    }
    for (int d = 32; d; d >>= 1) s += __shfl_xor(s, d);
    __shared__ float ps[4];
    __shared__ float sgain;
    if (lane == 0) ps[wid] = s;
    __syncthreads();
    if (tid == 0) {
        float total = ps[0] + ps[1] + ps[2] + ps[3];
        float ms   = total * (1.0f / (float)NS);
        float lufs = -0.691f + 10.0f * log10f(ms + 1e-8f);
        float gdb  = fminf(fmaxf(-23.0f - lufs, -30.0f), 30.0f);
        sgain = exp2f(gdb * 0.1660964047f);         // 10^(gdb/20)
    }
    __syncthreads();
    const float g = sgain;

    // ---- scale this block's segment ----
    const size_t base4 = (size_t)row * (NS / 4) + (size_t)seg * 4096;
    const f4* xi = reinterpret_cast<const f4*>(x) + base4;
    f4* oo = reinterpret_cast<f4*>(out) + base4;
#pragma unroll 4
    for (int k = 0; k < 16; ++k) {
        int i = k * BT + tid;
        f4 v = xi[i];                        // NORMAL load: exploit L3 residency
        v *= g;
        __builtin_nontemporal_store(v, oo + i);  // NT store: don't allocate L3
    }
}

extern "C" void kernel_launch(void* const* d_in, const int* in_sizes, int n_in,
                              void* d_out, int out_size, void* d_ws, size_t ws_size,
                              hipStream_t stream) {
    const float* x = (const float*)d_in[0];
    float* out = (float*)d_out;
    float* blk = (float*)d_ws;                 // NBLOCKS*3 floats

    k_scan<<<NBLOCKS, BT, 0, stream>>>(x, blk);
    k_scale<<<2048, BT, 0, stream>>>(x, blk, out);
}